// Round 1
// baseline (1950.858 us; speedup 1.0000x reference)
//
#include <hip/hip_runtime.h>

// ---------------------------------------------------------------------------
// Sparse UNet forward (f32, VALU version — round 1: correctness + structure)
//   BN(train) -> ReLU -> gather-GEMM chain per reference.
// ---------------------------------------------------------------------------

#define EPS 1e-4f

__global__ void zero_kernel(float* p, int n) {
    int i = blockIdx.x * 256 + threadIdx.x;
    if (i < n) p[i] = 0.f;
}

// Per-channel sum and sum-of-squares over `rows` rows of x (row stride `stride`).
// stats[0:C] += sum, stats[C:2C] += sumsq.
template <int C>
__global__ __launch_bounds__(256) void bn_stats(const float* __restrict__ x,
                                                int rows, int stride,
                                                float* __restrict__ stats) {
    const int tid = threadIdx.x;
    const int c = tid & (C - 1);
    const int g = tid / C;            // row group within block
    const int GR = 256 / C;           // row groups per block
    float s = 0.f, s2 = 0.f;
    for (int r = blockIdx.x * GR + g; r < rows; r += gridDim.x * GR) {
        float v = x[(size_t)r * stride + c];
        s += v;
        s2 += v * v;
    }
    __shared__ float sh[2][256];
    sh[0][tid] = s;
    sh[1][tid] = s2;
    __syncthreads();
    for (int off = 128; off >= C; off >>= 1) {
        if (tid < off) {
            sh[0][tid] += sh[0][tid + off];
            sh[1][tid] += sh[1][tid + off];
        }
        __syncthreads();
    }
    if (tid < C) {
        atomicAdd(&stats[c], sh[0][tid]);
        atomicAdd(&stats[C + c], sh[1][tid]);
    }
}

// y[r,c] = relu(gamma*(x-mu)*rsqrt(var+eps)+beta), written packed (rows+1)xC
// with sentinel row `rows` zeroed. Finalize of stats fused (cheap, L1-cached).
template <int C>
__global__ __launch_bounds__(256) void bn_norm_relu(const float* __restrict__ x,
                                                    int rows, int stride,
                                                    const float* __restrict__ stats,
                                                    const float* __restrict__ gamma,
                                                    const float* __restrict__ beta,
                                                    float* __restrict__ y) {
    size_t total = (size_t)(rows + 1) * C;
    size_t i = (size_t)blockIdx.x * 256 + threadIdx.x;
    if (i >= total) return;
    int c = (int)(i & (C - 1));
    int r = (int)(i / C);
    float out = 0.f;
    if (r < rows) {
        float inv_n = 1.0f / (float)rows;
        float mu = stats[c] * inv_n;
        float var = stats[C + c] * inv_n - mu * mu;
        float sc = gamma[c] * rsqrtf(var + EPS);
        float shf = beta[c] - mu * sc;
        float v = x[(size_t)r * stride + c];
        out = fmaxf(0.f, fmaf(v, sc, shf));
    }
    y[i] = out;
}

// Gather-GEMM: out[m, co] = sum_k sum_ci fpad[nbr[k*rows+m]][ci] * W[k][ci][co]
// fpad: (P+1) x CIN packed, row P = zeros (sentinel).
// Register tile 4x4 per thread; features staged transposed in LDS so compute
// reads ds_read_b128 over 4 rows; W read as coalesced float4 over 4 couts.
template <int CIN, int COUT, int TILE_M>
__global__ __launch_bounds__(256) void conv_tiled(const float* __restrict__ fpad,
                                                  const int* __restrict__ nbr,
                                                  const float* __restrict__ W,
                                                  float* __restrict__ out,
                                                  int rows, int K, int P,
                                                  int out_stride) {
    constexpr int TN = 4, TM = 4;
    constexpr int CO_G = COUT / TN;   // 8 or 16 co-groups
    constexpr int ROW_G = 256 / CO_G; // 32 or 16 row-groups
    static_assert(TILE_M == ROW_G * TM, "tile mismatch");

    __shared__ __align__(16) float sh[CIN][TILE_M]; // transposed feature tile
    __shared__ int sh_idx[TILE_M];

    const int tid = threadIdx.x;
    const int tx = tid % CO_G;
    const int ty = tid / CO_G;
    const int m0 = blockIdx.x * TILE_M;
    const int co0 = tx * TN;
    const int r0 = ty * TM;

    float acc[TM][TN];
#pragma unroll
    for (int m = 0; m < TM; m++)
#pragma unroll
        for (int n = 0; n < TN; n++) acc[m][n] = 0.f;

    for (int k = 0; k < K; k++) {
        __syncthreads(); // previous compute done before overwriting LDS
        if (tid < TILE_M) {
            int m = m0 + tid;
            sh_idx[tid] = (m < rows) ? nbr[(size_t)k * rows + m] : P;
        }
        __syncthreads();
        // gather: float4 over ci, scatter 4 scalar LDS writes (transposed)
        constexpr int E = TILE_M * (CIN / 4);
        for (int e = tid; e < E; e += 256) {
            int r = e % TILE_M;
            int c4 = e / TILE_M;
            const float4 v = ((const float4*)(fpad + (size_t)sh_idx[r] * CIN))[c4];
            sh[c4 * 4 + 0][r] = v.x;
            sh[c4 * 4 + 1][r] = v.y;
            sh[c4 * 4 + 2][r] = v.z;
            sh[c4 * 4 + 3][r] = v.w;
        }
        __syncthreads();
        const float* Wk = W + (size_t)k * CIN * COUT + co0;
#pragma unroll 4
        for (int ci = 0; ci < CIN; ci++) {
            float4 w = *(const float4*)(Wk + ci * COUT);
            float4 a = *(const float4*)(&sh[ci][r0]);
            float av[4] = {a.x, a.y, a.z, a.w};
            float wv[4] = {w.x, w.y, w.z, w.w};
#pragma unroll
            for (int m = 0; m < TM; m++)
#pragma unroll
                for (int n = 0; n < TN; n++) acc[m][n] = fmaf(av[m], wv[n], acc[m][n]);
        }
    }
#pragma unroll
    for (int m = 0; m < TM; m++) {
        int row = m0 + r0 + m;
        if (row < rows) {
            float4 v = make_float4(acc[m][0], acc[m][1], acc[m][2], acc[m][3]);
            *(float4*)(out + (size_t)row * out_stride + co0) = v;
        }
    }
}

// Stride-2 transpose conv: out[i, 32+co] = sum_ci cf[up_cidx[i]][ci] * W[up_k[i]][ci][co]
// Writes channels [32:64) of the concat buffer (row stride 64).
__global__ __launch_bounds__(256) void deconv_kernel(const float* __restrict__ cf,
                                                     const int* __restrict__ up_cidx,
                                                     const int* __restrict__ up_k,
                                                     const float* __restrict__ W, // [8][64][32]
                                                     float* __restrict__ cat, int Nrows) {
    int gid = blockIdx.x * 256 + threadIdx.x;
    int i = gid >> 5;
    int co = gid & 31;
    if (i >= Nrows) return;
    int c = up_cidx[i];
    int k = up_k[i];
    const float* g = cf + (size_t)c * 64;
    const float* Wk = W + (size_t)k * 64 * 32 + co;
    float acc = 0.f;
#pragma unroll 8
    for (int ci = 0; ci < 64; ci++) acc = fmaf(g[ci], Wk[ci * 32], acc);
    cat[(size_t)i * 64 + 32 + co] = acc;
}

static inline int ceil_div(long a, long b) { return (int)((a + b - 1) / b); }

extern "C" void kernel_launch(void* const* d_in, const int* in_sizes, int n_in,
                              void* d_out, int out_size, void* d_ws, size_t ws_size,
                              hipStream_t stream) {
    const float* feat   = (const float*)d_in[0];
    const float* w_sub1 = (const float*)d_in[1];
    const float* w_down = (const float*)d_in[2];
    const float* w_sub2 = (const float*)d_in[3];
    const float* w_up   = (const float*)d_in[4];
    const float* w_sub3 = (const float*)d_in[5];
    const float* g1 = (const float*)d_in[6],  *b1 = (const float*)d_in[7];
    const float* g2 = (const float*)d_in[8],  *b2 = (const float*)d_in[9];
    const float* g3 = (const float*)d_in[10], *b3 = (const float*)d_in[11];
    const float* g4 = (const float*)d_in[12], *b4 = (const float*)d_in[13];
    const float* g5 = (const float*)d_in[14], *b5 = (const float*)d_in[15];
    const int* nbr_fine   = (const int*)d_in[16];
    const int* nbr_coarse = (const int*)d_in[17];
    const int* down_idx   = (const int*)d_in[18];
    const int* up_cidx    = (const int*)d_in[19];
    const int* up_k       = (const int*)d_in[20];

    const int N = in_sizes[0] / 32;
    const int M = in_sizes[17] / 27;

    char* ws = (char*)d_ws;
    float* stats = (float*)ws;         // 5 slots x 128 floats
    size_t off = 4096;
    size_t maxr = (size_t)((N > M ? N : M) + 1);
    size_t SZ = ((maxr * 64 * sizeof(float)) + 255) & ~(size_t)255;
    float* A = (float*)(ws + off); off += SZ;
    float* B = (float*)(ws + off); off += SZ;
    float* C = (float*)(ws + off); off += SZ;
    float* D = (float*)(ws + off); off += SZ;  // concat buffer [skip | up]

    float* st0 = stats + 0 * 128;
    float* st1 = stats + 1 * 128;
    float* st2 = stats + 2 * 128;
    float* st3 = stats + 3 * 128;
    float* st4 = stats + 4 * 128;

    zero_kernel<<<3, 256, 0, stream>>>(stats, 5 * 128);

    // 1) BN0+ReLU(feat) -> A  [(N+1)x32]
    bn_stats<32><<<256, 256, 0, stream>>>(feat, N, 32, st0);
    bn_norm_relu<32><<<ceil_div((long)(N + 1) * 32, 256), 256, 0, stream>>>(
        feat, N, 32, st0, g1, b1, A);
    // 2) conv1 (27, 32->32): A -> D[:,0:32] (skip), row stride 64
    conv_tiled<32, 32, 128><<<ceil_div(N, 128), 256, 0, stream>>>(
        A, nbr_fine, w_sub1, D, N, 27, N, 64);
    // 3) BN1+ReLU(skip) -> B  [(N+1)x32]
    bn_stats<32><<<256, 256, 0, stream>>>(D, N, 64, st1);
    bn_norm_relu<32><<<ceil_div((long)(N + 1) * 32, 256), 256, 0, stream>>>(
        D, N, 64, st1, g2, b2, B);
    // 4) down conv (8, 32->64): B -> C (xc1, Mx64)
    conv_tiled<32, 64, 64><<<ceil_div(M, 64), 256, 0, stream>>>(
        B, down_idx, w_down, C, M, 8, N, 64);
    // 5) BN2+ReLU(xc1) -> A  [(M+1)x64]
    bn_stats<64><<<256, 256, 0, stream>>>(C, M, 64, st2);
    bn_norm_relu<64><<<ceil_div((long)(M + 1) * 64, 256), 256, 0, stream>>>(
        C, M, 64, st2, g3, b3, A);
    // 6) conv2 (27, 64->64): A -> B (xc2, Mx64)
    conv_tiled<64, 64, 64><<<ceil_div(M, 64), 256, 0, stream>>>(
        A, nbr_coarse, w_sub2, B, M, 27, M, 64);
    // 7) BN3+ReLU(xc2) -> C  [(M+1)x64]
    bn_stats<64><<<256, 256, 0, stream>>>(B, M, 64, st3);
    bn_norm_relu<64><<<ceil_div((long)(M + 1) * 64, 256), 256, 0, stream>>>(
        B, M, 64, st3, g4, b4, C);
    // 8) deconv (64->32): C -> D[:,32:64]
    deconv_kernel<<<ceil_div((long)N * 32, 256), 256, 0, stream>>>(
        C, up_cidx, up_k, w_up, D, N);
    // 9) BN4+ReLU(cat) -> A  [(N+1)x64]
    bn_stats<64><<<256, 256, 0, stream>>>(D, N, 64, st4);
    bn_norm_relu<64><<<ceil_div((long)(N + 1) * 64, 256), 256, 0, stream>>>(
        D, N, 64, st4, g5, b5, A);
    // 10) conv3 (27, 64->32): A -> d_out (Nx32)
    conv_tiled<64, 32, 128><<<ceil_div(N, 128), 256, 0, stream>>>(
        A, nbr_fine, w_sub3, (float*)d_out, N, 27, N, 32);
}

// Round 2
// 1034.968 us; speedup vs baseline: 1.8849x; 1.8849x over previous
//
#include <hip/hip_runtime.h>

// ---------------------------------------------------------------------------
// Sparse UNet forward — round 2: bf16 MFMA gather-GEMMs, f32 accumulate.
//   BN stats stay f32 (conv outputs are f32); BN outputs written bf16 and
//   consumed by MFMA convs via LDS-staged gathers.
// ---------------------------------------------------------------------------

#define EPS 1e-4f

typedef __attribute__((ext_vector_type(8))) short short8;   // 8 x bf16
typedef __attribute__((ext_vector_type(4))) float f32x4;

__device__ __forceinline__ unsigned short f2bf(float f) {
    union { float f; unsigned int u; } v; v.f = f;
    unsigned int r = v.u + 0x7fffu + ((v.u >> 16) & 1u);   // RNE
    return (unsigned short)(r >> 16);
}
__device__ __forceinline__ float bf2f(unsigned short h) {
    union { unsigned int u; float f; } v; v.u = ((unsigned int)h) << 16;
    return v.f;
}

__global__ void zero_kernel(float* p, int n) {
    int i = blockIdx.x * 256 + threadIdx.x;
    if (i < n) p[i] = 0.f;
}

// Per-channel sum / sumsq, atomically accumulated into stats[0:C], stats[C:2C].
template <int C>
__global__ __launch_bounds__(256) void bn_stats(const float* __restrict__ x,
                                                int rows, int stride,
                                                float* __restrict__ stats) {
    const int tid = threadIdx.x;
    const int c = tid & (C - 1);
    const int g = tid / C;
    const int GR = 256 / C;
    float s = 0.f, s2 = 0.f;
    for (int r = blockIdx.x * GR + g; r < rows; r += gridDim.x * GR) {
        float v = x[(size_t)r * stride + c];
        s += v; s2 += v * v;
    }
    __shared__ float sh[2][256];
    sh[0][tid] = s; sh[1][tid] = s2;
    __syncthreads();
    for (int off = 128; off >= C; off >>= 1) {
        if (tid < off) { sh[0][tid] += sh[0][tid + off]; sh[1][tid] += sh[1][tid + off]; }
        __syncthreads();
    }
    if (tid < C) {
        atomicAdd(&stats[c], sh[0][tid]);
        atomicAdd(&stats[C + c], sh[1][tid]);
    }
}

// BN finalize + ReLU, output packed bf16 (rows+1) x C with zero sentinel row.
template <int C>
__global__ __launch_bounds__(256) void bn_norm_relu_bf16(
    const float* __restrict__ x, int rows, int stride,
    const float* __restrict__ stats,
    const float* __restrict__ gamma, const float* __restrict__ beta,
    unsigned short* __restrict__ y) {
    size_t total = (size_t)(rows + 1) * C;
    size_t i = (size_t)blockIdx.x * 256 + threadIdx.x;
    if (i >= total) return;
    int c = (int)(i & (C - 1));
    int r = (int)(i / C);
    float out = 0.f;
    if (r < rows) {
        float inv_n = 1.0f / (float)rows;
        float mu = stats[c] * inv_n;
        float var = stats[C + c] * inv_n - mu * mu;
        float sc = gamma[c] * rsqrtf(var + EPS);
        float shf = beta[c] - mu * sc;
        float v = x[(size_t)r * stride + c];
        out = fmaxf(0.f, fmaf(v, sc, shf));
    }
    y[i] = f2bf(out);
}

// W [K][CIN][COUT] f32 -> WT [K][COUT][CIN] bf16 (B-fragment friendly).
template <int CIN, int COUT>
__global__ void wt_transpose(const float* __restrict__ W, unsigned short* __restrict__ WT, int K) {
    int id = blockIdx.x * 256 + threadIdx.x;
    int total = K * CIN * COUT;
    if (id >= total) return;
    int t = id / (CIN * COUT);
    int r = id % (CIN * COUT);
    int co = r / CIN;
    int ci = r % CIN;
    WT[id] = f2bf(W[(size_t)t * CIN * COUT + ci * COUT + co]);
}

__global__ void wt_cast(const float* __restrict__ W, unsigned short* __restrict__ WT, int total) {
    int id = blockIdx.x * 256 + threadIdx.x;
    if (id < total) WT[id] = f2bf(W[id]);
}

// Gather-GEMM with MFMA 16x16x32 bf16.
//   fpad: (P+1) x CIN bf16 packed, row P zeros.  WT: [K][COUT][CIN] bf16.
//   out[m, co] (f32, stride out_stride) = sum_k fpad[nbr[k,m]] @ W[k]
template <int CIN, int COUT, int TILE_M>
__global__ __launch_bounds__(256) void conv_mfma(
    const unsigned short* __restrict__ fpad,
    const int* __restrict__ nbr,
    const unsigned short* __restrict__ WT,
    float* __restrict__ out,
    int rows, int K, int P, int out_stride) {
    constexpr int CPR = CIN / 8;            // 16B chunks per row
    constexpr int STRIDE = CIN + 8;         // elems; 80B / 144B rows (16B-mult)
    constexpr int WAVE_M = TILE_M / 4;      // rows per wave
    constexpr int M_SUB = WAVE_M / 16;
    constexpr int N_SUB = COUT / 16;
    constexpr int K_SUB = CIN / 32;
    __shared__ __align__(16) unsigned short shA[TILE_M * STRIDE];

    const int tid = threadIdx.x;
    const int wave = tid >> 6;
    const int lane = tid & 63;
    const int q = lane >> 4;       // quad 0..3
    const int l15 = lane & 15;
    const int m0 = blockIdx.x * TILE_M;

    f32x4 acc[M_SUB][N_SUB];
#pragma unroll
    for (int mt = 0; mt < M_SUB; ++mt)
#pragma unroll
        for (int nt = 0; nt < N_SUB; ++nt) acc[mt][nt] = (f32x4){0.f, 0.f, 0.f, 0.f};

    for (int k = 0; k < K; ++k) {
        __syncthreads();   // previous tap's reads of shA done
#pragma unroll
        for (int it = 0; it < (TILE_M * CPR) / 256; ++it) {
            int c = tid + it * 256;
            int r = c / CPR;
            int ch = c % CPR;
            int m = m0 + r;
            int idx = (m < rows) ? nbr[(size_t)k * rows + m] : P;
            uint4 v = *(const uint4*)(fpad + (size_t)idx * CIN + ch * 8);
            *(uint4*)(&shA[r * STRIDE + ch * 8]) = v;
        }
        __syncthreads();
        const unsigned short* Wk = WT + (size_t)k * COUT * CIN;
        short8 bfrag[N_SUB][K_SUB];
#pragma unroll
        for (int nt = 0; nt < N_SUB; ++nt)
#pragma unroll
            for (int kf = 0; kf < K_SUB; ++kf)
                bfrag[nt][kf] = *(const short8*)(Wk + (size_t)(nt * 16 + l15) * CIN + kf * 32 + q * 8);
#pragma unroll
        for (int mt = 0; mt < M_SUB; ++mt) {
            const int row = wave * WAVE_M + mt * 16 + l15;
            short8 afrag[K_SUB];
#pragma unroll
            for (int kf = 0; kf < K_SUB; ++kf)
                afrag[kf] = *(const short8*)(&shA[row * STRIDE + kf * 32 + q * 8]);
#pragma unroll
            for (int nt = 0; nt < N_SUB; ++nt)
#pragma unroll
                for (int kf = 0; kf < K_SUB; ++kf)
                    acc[mt][nt] = __builtin_amdgcn_mfma_f32_16x16x32_bf16(
                        afrag[kf], bfrag[nt][kf], acc[mt][nt], 0, 0, 0);
        }
    }
    // C/D layout: col = lane&15, row = quad*4 + reg  [measured m89/m91]
#pragma unroll
    for (int mt = 0; mt < M_SUB; ++mt)
#pragma unroll
        for (int i = 0; i < 4; ++i) {
            int row = m0 + wave * WAVE_M + mt * 16 + q * 4 + i;
            if (row < rows) {
#pragma unroll
                for (int nt = 0; nt < N_SUB; ++nt)
                    out[(size_t)row * out_stride + nt * 16 + l15] = acc[mt][nt][i];
            }
        }
}

// Stride-2 transpose conv: cat[i, 32+co] = cf[up_cidx[i]] . Wup[up_k[i]][:, co]
// 8 threads per fine row, 4 couts each; bf16 inputs, f32 accum.
__global__ __launch_bounds__(256) void deconv_kernel(
    const unsigned short* __restrict__ cf,     // (M+1) x 64 bf16
    const int* __restrict__ up_cidx, const int* __restrict__ up_k,
    const unsigned short* __restrict__ Wup,    // [8][64][32] bf16
    float* __restrict__ cat, int Nrows) {
    int gid = blockIdx.x * 256 + threadIdx.x;
    int i = gid >> 3;
    int t = gid & 7;
    if (i >= Nrows) return;
    int c = up_cidx[i];
    int kk = up_k[i];
    const unsigned short* g = cf + (size_t)c * 64;
    const unsigned short* Wk = Wup + (size_t)kk * 64 * 32 + t * 4;
    float a0 = 0.f, a1 = 0.f, a2 = 0.f, a3 = 0.f;
#pragma unroll
    for (int ci8 = 0; ci8 < 64; ci8 += 8) {
        short8 gv = *(const short8*)(g + ci8);
#pragma unroll
        for (int j = 0; j < 8; ++j) {
            float gf = bf2f((unsigned short)gv[j]);
            const unsigned short* w = Wk + (ci8 + j) * 32;
            a0 = fmaf(gf, bf2f(w[0]), a0);
            a1 = fmaf(gf, bf2f(w[1]), a1);
            a2 = fmaf(gf, bf2f(w[2]), a2);
            a3 = fmaf(gf, bf2f(w[3]), a3);
        }
    }
    float* o = cat + (size_t)i * 64 + 32 + t * 4;
    o[0] = a0; o[1] = a1; o[2] = a2; o[3] = a3;
}

static inline int ceil_div(long a, long b) { return (int)((a + b - 1) / b); }

extern "C" void kernel_launch(void* const* d_in, const int* in_sizes, int n_in,
                              void* d_out, int out_size, void* d_ws, size_t ws_size,
                              hipStream_t stream) {
    const float* feat   = (const float*)d_in[0];
    const float* w_sub1 = (const float*)d_in[1];
    const float* w_down = (const float*)d_in[2];
    const float* w_sub2 = (const float*)d_in[3];
    const float* w_up   = (const float*)d_in[4];
    const float* w_sub3 = (const float*)d_in[5];
    const float* g1 = (const float*)d_in[6],  *b1 = (const float*)d_in[7];
    const float* g2 = (const float*)d_in[8],  *b2 = (const float*)d_in[9];
    const float* g3 = (const float*)d_in[10], *b3 = (const float*)d_in[11];
    const float* g4 = (const float*)d_in[12], *b4 = (const float*)d_in[13];
    const float* g5 = (const float*)d_in[14], *b5 = (const float*)d_in[15];
    const int* nbr_fine   = (const int*)d_in[16];
    const int* nbr_coarse = (const int*)d_in[17];
    const int* down_idx   = (const int*)d_in[18];
    const int* up_cidx    = (const int*)d_in[19];
    const int* up_k       = (const int*)d_in[20];

    const int N = in_sizes[0] / 32;
    const int M = in_sizes[17] / 27;
    const size_t maxr = (size_t)((N > M ? N : M) + 1);

    char* ws = (char*)d_ws;
    size_t off = 0;
    auto alloc = [&](size_t bytes) { void* p = ws + off; off += (bytes + 255) & ~(size_t)255; return p; };
    float* stats = (float*)alloc(5 * 128 * sizeof(float));
    float* D  = (float*)alloc((size_t)N * 64 * sizeof(float));        // concat buf [skip|up]
    float* Cf = (float*)alloc((size_t)M * 64 * sizeof(float));        // coarse f32 temp
    unsigned short* FA = (unsigned short*)alloc(maxr * 64 * 2);       // bf16 features A
    unsigned short* FB = (unsigned short*)alloc(maxr * 64 * 2);       // bf16 features B
    unsigned short* w1t = (unsigned short*)alloc(27 * 32 * 32 * 2);
    unsigned short* wdt = (unsigned short*)alloc(8 * 32 * 64 * 2);
    unsigned short* w2t = (unsigned short*)alloc(27 * 64 * 64 * 2);
    unsigned short* w3t = (unsigned short*)alloc(27 * 64 * 32 * 2);
    unsigned short* wup = (unsigned short*)alloc(8 * 64 * 32 * 2);

    float* st0 = stats + 0 * 128;
    float* st1 = stats + 1 * 128;
    float* st2 = stats + 2 * 128;
    float* st3 = stats + 3 * 128;
    float* st4 = stats + 4 * 128;

    zero_kernel<<<3, 256, 0, stream>>>(stats, 5 * 128);
    wt_transpose<32, 32><<<ceil_div(27 * 32 * 32, 256), 256, 0, stream>>>(w_sub1, w1t, 27);
    wt_transpose<32, 64><<<ceil_div(8 * 32 * 64, 256), 256, 0, stream>>>(w_down, wdt, 8);
    wt_transpose<64, 64><<<ceil_div(27 * 64 * 64, 256), 256, 0, stream>>>(w_sub2, w2t, 27);
    wt_transpose<64, 32><<<ceil_div(27 * 64 * 32, 256), 256, 0, stream>>>(w_sub3, w3t, 27);
    wt_cast<<<ceil_div(8 * 64 * 32, 256), 256, 0, stream>>>(w_up, wup, 8 * 64 * 32);

    // 1) BN0+ReLU(feat) -> FA [(N+1)x32 bf16]
    bn_stats<32><<<256, 256, 0, stream>>>(feat, N, 32, st0);
    bn_norm_relu_bf16<32><<<ceil_div((long)(N + 1) * 32, 256), 256, 0, stream>>>(
        feat, N, 32, st0, g1, b1, FA);
    // 2) conv1 (27, 32->32): FA -> D[:,0:32] (skip)
    conv_mfma<32, 32, 128><<<ceil_div(N, 128), 256, 0, stream>>>(
        FA, nbr_fine, w1t, D, N, 27, N, 64);
    // 3) BN1+ReLU(skip) -> FB [(N+1)x32]
    bn_stats<32><<<256, 256, 0, stream>>>(D, N, 64, st1);
    bn_norm_relu_bf16<32><<<ceil_div((long)(N + 1) * 32, 256), 256, 0, stream>>>(
        D, N, 64, st1, g2, b2, FB);
    // 4) down conv (8, 32->64): FB -> Cf (M x 64 f32)
    conv_mfma<32, 64, 128><<<ceil_div(M, 128), 256, 0, stream>>>(
        FB, down_idx, wdt, Cf, M, 8, N, 64);
    // 5) BN2+ReLU(Cf) -> FA [(M+1)x64]
    bn_stats<64><<<256, 256, 0, stream>>>(Cf, M, 64, st2);
    bn_norm_relu_bf16<64><<<ceil_div((long)(M + 1) * 64, 256), 256, 0, stream>>>(
        Cf, M, 64, st2, g3, b3, FA);
    // 6) conv2 (27, 64->64): FA -> Cf (reuse, safe: BN2 already consumed it)
    conv_mfma<64, 64, 128><<<ceil_div(M, 128), 256, 0, stream>>>(
        FA, nbr_coarse, w2t, Cf, M, 27, M, 64);
    // 7) BN3+ReLU(Cf) -> FB [(M+1)x64]
    bn_stats<64><<<256, 256, 0, stream>>>(Cf, M, 64, st3);
    bn_norm_relu_bf16<64><<<ceil_div((long)(M + 1) * 64, 256), 256, 0, stream>>>(
        Cf, M, 64, st3, g4, b4, FB);
    // 8) deconv (64->32): FB -> D[:,32:64]
    deconv_kernel<<<ceil_div((long)N * 8, 256), 256, 0, stream>>>(
        FB, up_cidx, up_k, wup, D, N);
    // 9) BN4+ReLU(D) -> FA [(N+1)x64]
    bn_stats<64><<<256, 256, 0, stream>>>(D, N, 64, st4);
    bn_norm_relu_bf16<64><<<ceil_div((long)(N + 1) * 64, 256), 256, 0, stream>>>(
        D, N, 64, st4, g5, b5, FA);
    // 10) conv3 (27, 64->32): FA -> d_out (N x 32 f32)
    conv_mfma<64, 32, 128><<<ceil_div(N, 128), 256, 0, stream>>>(
        FA, nbr_fine, w3t, (float*)d_out, N, 27, N, 32);
}

// Round 3
// 819.657 us; speedup vs baseline: 2.3801x; 1.2627x over previous
//
#include <hip/hip_runtime.h>

// ---------------------------------------------------------------------------
// Sparse UNet forward — round 3: barrier-free direct-fragment gather MFMA.
//   The MFMA A-fragment (lane l15,q -> 16B of row idx[l15] at offset q*8)
//   is gathered straight from global memory; no LDS, no __syncthreads in the
//   conv kernels. 2-stage register ping-pong pipeline across taps.
// ---------------------------------------------------------------------------

#define EPS 1e-4f

typedef __attribute__((ext_vector_type(8))) short short8;   // 8 x bf16
typedef __attribute__((ext_vector_type(4))) float f32x4;

__device__ __forceinline__ unsigned short f2bf(float f) {
    union { float f; unsigned int u; } v; v.f = f;
    unsigned int r = v.u + 0x7fffu + ((v.u >> 16) & 1u);   // RNE
    return (unsigned short)(r >> 16);
}
__device__ __forceinline__ float bf2f(unsigned short h) {
    union { unsigned int u; float f; } v; v.u = ((unsigned int)h) << 16;
    return v.f;
}

__global__ void zero_kernel(float* p, int n) {
    int i = blockIdx.x * 256 + threadIdx.x;
    if (i < n) p[i] = 0.f;
}

// Per-channel sum / sumsq, atomically accumulated into stats[0:C], stats[C:2C].
template <int C>
__global__ __launch_bounds__(256) void bn_stats(const float* __restrict__ x,
                                                int rows, int stride,
                                                float* __restrict__ stats) {
    const int tid = threadIdx.x;
    const int c = tid & (C - 1);
    const int g = tid / C;
    const int GR = 256 / C;
    float s = 0.f, s2 = 0.f;
    for (int r = blockIdx.x * GR + g; r < rows; r += gridDim.x * GR) {
        float v = x[(size_t)r * stride + c];
        s += v; s2 += v * v;
    }
    __shared__ float sh[2][256];
    sh[0][tid] = s; sh[1][tid] = s2;
    __syncthreads();
    for (int off = 128; off >= C; off >>= 1) {
        if (tid < off) { sh[0][tid] += sh[0][tid + off]; sh[1][tid] += sh[1][tid + off]; }
        __syncthreads();
    }
    if (tid < C) {
        atomicAdd(&stats[c], sh[0][tid]);
        atomicAdd(&stats[C + c], sh[1][tid]);
    }
}

// BN finalize + ReLU -> bf16, vectorized 8 channels/thread.
// Output packed (rows+1) x C, sentinel row `rows` zeroed.
// Stats for channel c come from stA if c < CSPLIT else stB (at c-CSPLIT),
// each laid out [Cs sums][Cs sumsqs] with Cs = CSPLIT / (C-CSPLIT).
template <int C, int CSPLIT>
__global__ __launch_bounds__(256) void bn_norm_relu_bf16(
    const float* __restrict__ x, int rows, int stride,
    const float* __restrict__ stA, const float* __restrict__ stB,
    const float* __restrict__ gamma, const float* __restrict__ beta,
    unsigned short* __restrict__ y) {
    constexpr int TPR = C / 8;
    int gid = blockIdx.x * 256 + threadIdx.x;
    int r = gid / TPR, t = gid % TPR;
    if (r > rows) return;
    short8 o8;
    if (r == rows) {
        for (int j = 0; j < 8; ++j) o8[j] = 0;
    } else {
        const float inv_n = 1.0f / (float)rows;
        const float* xr = x + (size_t)r * stride + t * 8;
        float4 v0 = *(const float4*)(xr);
        float4 v1 = *(const float4*)(xr + 4);
        float vv[8] = {v0.x, v0.y, v0.z, v0.w, v1.x, v1.y, v1.z, v1.w};
#pragma unroll
        for (int j = 0; j < 8; ++j) {
            int c = t * 8 + j;
            const float* st = (c < CSPLIT) ? stA : stB;
            int cc = (c < CSPLIT) ? c : c - CSPLIT;
            int cs = (c < CSPLIT) ? CSPLIT : (C - CSPLIT);
            float mu = st[cc] * inv_n;
            float var = st[cs + cc] * inv_n - mu * mu;
            float sc = gamma[c] * rsqrtf(var + EPS);
            float shf = beta[c] - mu * sc;
            float ov = fmaxf(0.f, fmaf(vv[j], sc, shf));
            o8[j] = (short)f2bf(ov);
        }
    }
    *(short8*)(y + (size_t)r * C + t * 8) = o8;
}

// W [K][CIN][COUT] f32 -> WT [K][COUT][CIN] bf16 (B-fragment friendly).
template <int CIN, int COUT>
__global__ void wt_transpose(const float* __restrict__ W, unsigned short* __restrict__ WT, int K) {
    int id = blockIdx.x * 256 + threadIdx.x;
    int total = K * CIN * COUT;
    if (id >= total) return;
    int t = id / (CIN * COUT);
    int r = id % (CIN * COUT);
    int co = r / CIN;
    int ci = r % CIN;
    WT[id] = f2bf(W[(size_t)t * CIN * COUT + ci * COUT + co]);
}

__global__ void wt_cast(const float* __restrict__ W, unsigned short* __restrict__ WT, int total) {
    int id = blockIdx.x * 256 + threadIdx.x;
    if (id < total) WT[id] = f2bf(W[id]);
}

// Barrier-free gather-GEMM, MFMA 16x16x32 bf16, direct fragment gather.
//   fpad: (P+1) x CIN bf16, row P zeros.  WT: [K][COUT][CIN] bf16.
//   out[m, co] += over taps; f32, row stride out_stride.
// Each wave owns M_SUB 16-row tiles; 4 waves/block; no shared state.
template <int CIN, int COUT, int M_SUB>
__global__ __launch_bounds__(256) void conv_mfma_direct(
    const unsigned short* __restrict__ fpad,
    const int* __restrict__ nbr,
    const unsigned short* __restrict__ WT,
    float* __restrict__ out,
    int rows, int K, int P, int out_stride) {
    constexpr int N_SUB = COUT / 16;
    constexpr int K_SUB = CIN / 32;
    const int tid = threadIdx.x;
    const int wave = tid >> 6;
    const int lane = tid & 63;
    const int q = lane >> 4;
    const int l15 = lane & 15;
    const int m0 = blockIdx.x * (4 * M_SUB * 16) + wave * (M_SUB * 16);

    f32x4 acc[M_SUB][N_SUB];
#pragma unroll
    for (int mt = 0; mt < M_SUB; ++mt)
#pragma unroll
        for (int nt = 0; nt < N_SUB; ++nt) acc[mt][nt] = (f32x4){0.f, 0.f, 0.f, 0.f};

    int idxA[M_SUB], idxB[M_SUB];
    short8 aA[M_SUB][K_SUB], aB[M_SUB][K_SUB];
    short8 bA[N_SUB][K_SUB], bB[N_SUB][K_SUB];

    auto load_idx = [&](int k, int (&dst)[M_SUB]) {
#pragma unroll
        for (int mt = 0; mt < M_SUB; ++mt) {
            int m = m0 + mt * 16 + l15;
            dst[mt] = (m < rows) ? nbr[(size_t)k * rows + m] : P;
        }
    };
    auto load_a = [&](const int (&src)[M_SUB], short8 (&dst)[M_SUB][K_SUB]) {
#pragma unroll
        for (int mt = 0; mt < M_SUB; ++mt)
#pragma unroll
            for (int kf = 0; kf < K_SUB; ++kf)
                dst[mt][kf] = *(const short8*)(fpad + (size_t)src[mt] * CIN + kf * 32 + q * 8);
    };
    auto load_b = [&](int k, short8 (&dst)[N_SUB][K_SUB]) {
        const unsigned short* Wk = WT + (size_t)k * COUT * CIN;
#pragma unroll
        for (int nt = 0; nt < N_SUB; ++nt)
#pragma unroll
            for (int kf = 0; kf < K_SUB; ++kf)
                dst[nt][kf] = *(const short8*)(Wk + (size_t)(nt * 16 + l15) * CIN + kf * 32 + q * 8);
    };
    auto compute = [&](short8 (&a)[M_SUB][K_SUB], short8 (&b)[N_SUB][K_SUB]) {
#pragma unroll
        for (int mt = 0; mt < M_SUB; ++mt)
#pragma unroll
            for (int nt = 0; nt < N_SUB; ++nt)
#pragma unroll
                for (int kf = 0; kf < K_SUB; ++kf)
                    acc[mt][nt] = __builtin_amdgcn_mfma_f32_16x16x32_bf16(
                        a[mt][kf], b[nt][kf], acc[mt][nt], 0, 0, 0);
    };

    // Prologue: frags for tap 0 in set A; idxA = indices for tap 1.
    {
        int tmp[M_SUB];
        load_idx(0, tmp);
        load_a(tmp, aA);
        load_b(0, bA);
        if (K > 1) load_idx(1, idxA);
    }
    int k = 0;
    for (; k + 1 < K; k += 2) {
        // step A -> B at tap k
        load_a(idxA, aB);
        load_b(k + 1, bB);
        load_idx((k + 2 < K) ? k + 2 : 0, idxB);
        compute(aA, bA);
        // step B -> A at tap k+1
        if (k + 2 < K) {
            load_a(idxB, aA);
            load_b(k + 2, bA);
            load_idx((k + 3 < K) ? k + 3 : 0, idxA);
        }
        compute(aB, bB);
    }
    if (k < K) compute(aA, bA);   // odd K tail (tap K-1 staged in set A)

    // C/D layout: col = lane&15, row = q*4 + reg  [measured m89/m91]
#pragma unroll
    for (int mt = 0; mt < M_SUB; ++mt)
#pragma unroll
        for (int i = 0; i < 4; ++i) {
            int row = m0 + mt * 16 + q * 4 + i;
            if (row < rows) {
#pragma unroll
                for (int nt = 0; nt < N_SUB; ++nt)
                    out[(size_t)row * out_stride + nt * 16 + l15] = acc[mt][nt][i];
            }
        }
}

// Stride-2 transpose conv: cat[i, 32+co] = cf[up_cidx[i]] . Wup[up_k[i]][:, co]
__global__ __launch_bounds__(256) void deconv_kernel(
    const unsigned short* __restrict__ cf,     // (M+1) x 64 bf16
    const int* __restrict__ up_cidx, const int* __restrict__ up_k,
    const unsigned short* __restrict__ Wup,    // [8][64][32] bf16
    float* __restrict__ cat, int Nrows) {
    int gid = blockIdx.x * 256 + threadIdx.x;
    int i = gid >> 3;
    int t = gid & 7;
    if (i >= Nrows) return;
    int c = up_cidx[i];
    int kk = up_k[i];
    const unsigned short* g = cf + (size_t)c * 64;
    const unsigned short* Wk = Wup + (size_t)kk * 64 * 32 + t * 4;
    float a0 = 0.f, a1 = 0.f, a2 = 0.f, a3 = 0.f;
#pragma unroll
    for (int ci8 = 0; ci8 < 64; ci8 += 8) {
        short8 gv = *(const short8*)(g + ci8);
#pragma unroll
        for (int j = 0; j < 8; ++j) {
            float gf = bf2f((unsigned short)gv[j]);
            const unsigned short* w = Wk + (ci8 + j) * 32;
            a0 = fmaf(gf, bf2f(w[0]), a0);
            a1 = fmaf(gf, bf2f(w[1]), a1);
            a2 = fmaf(gf, bf2f(w[2]), a2);
            a3 = fmaf(gf, bf2f(w[3]), a3);
        }
    }
    float* o = cat + (size_t)i * 64 + 32 + t * 4;
    o[0] = a0; o[1] = a1; o[2] = a2; o[3] = a3;
}

static inline int ceil_div(long a, long b) { return (int)((a + b - 1) / b); }

extern "C" void kernel_launch(void* const* d_in, const int* in_sizes, int n_in,
                              void* d_out, int out_size, void* d_ws, size_t ws_size,
                              hipStream_t stream) {
    const float* feat   = (const float*)d_in[0];
    const float* w_sub1 = (const float*)d_in[1];
    const float* w_down = (const float*)d_in[2];
    const float* w_sub2 = (const float*)d_in[3];
    const float* w_up   = (const float*)d_in[4];
    const float* w_sub3 = (const float*)d_in[5];
    const float* g1 = (const float*)d_in[6],  *b1 = (const float*)d_in[7];
    const float* g2 = (const float*)d_in[8],  *b2 = (const float*)d_in[9];
    const float* g3 = (const float*)d_in[10], *b3 = (const float*)d_in[11];
    const float* g4 = (const float*)d_in[12], *b4 = (const float*)d_in[13];
    const float* g5 = (const float*)d_in[14], *b5 = (const float*)d_in[15];
    const int* nbr_fine   = (const int*)d_in[16];
    const int* nbr_coarse = (const int*)d_in[17];
    const int* down_idx   = (const int*)d_in[18];
    const int* up_cidx    = (const int*)d_in[19];
    const int* up_k       = (const int*)d_in[20];

    const int N = in_sizes[0] / 32;
    const int M = in_sizes[17] / 27;
    const size_t maxr = (size_t)((N > M ? N : M) + 1);

    char* ws = (char*)d_ws;
    size_t off = 0;
    auto alloc = [&](size_t bytes) { void* p = ws + off; off += (bytes + 255) & ~(size_t)255; return p; };
    float* stats = (float*)alloc(6 * 128 * sizeof(float));
    float* D  = (float*)alloc((size_t)N * 64 * sizeof(float));        // concat buf [skip|up]
    float* Cf = (float*)alloc((size_t)M * 64 * sizeof(float));        // coarse f32 temp
    unsigned short* FA = (unsigned short*)alloc(maxr * 64 * 2);       // bf16 features A
    unsigned short* FB = (unsigned short*)alloc(maxr * 64 * 2);       // bf16 features B
    unsigned short* w1t = (unsigned short*)alloc(27 * 32 * 32 * 2);
    unsigned short* wdt = (unsigned short*)alloc(8 * 32 * 64 * 2);
    unsigned short* w2t = (unsigned short*)alloc(27 * 64 * 64 * 2);
    unsigned short* w3t = (unsigned short*)alloc(27 * 64 * 32 * 2);
    unsigned short* wup = (unsigned short*)alloc(8 * 64 * 32 * 2);

    float* st0 = stats + 0 * 128;
    float* st1 = stats + 1 * 128;
    float* st2 = stats + 2 * 128;
    float* st3 = stats + 3 * 128;
    float* st4 = stats + 4 * 128;   // deconv-half stats (32 ch) of concat

    zero_kernel<<<3, 256, 0, stream>>>(stats, 6 * 128);
    wt_transpose<32, 32><<<ceil_div(27 * 32 * 32, 256), 256, 0, stream>>>(w_sub1, w1t, 27);
    wt_transpose<32, 64><<<ceil_div(8 * 32 * 64, 256), 256, 0, stream>>>(w_down, wdt, 8);
    wt_transpose<64, 64><<<ceil_div(27 * 64 * 64, 256), 256, 0, stream>>>(w_sub2, w2t, 27);
    wt_transpose<64, 32><<<ceil_div(27 * 64 * 32, 256), 256, 0, stream>>>(w_sub3, w3t, 27);
    wt_cast<<<ceil_div(8 * 64 * 32, 256), 256, 0, stream>>>(w_up, wup, 8 * 64 * 32);

    // 1) BN0+ReLU(feat) -> FA [(N+1)x32 bf16]
    bn_stats<32><<<256, 256, 0, stream>>>(feat, N, 32, st0);
    bn_norm_relu_bf16<32, 32><<<ceil_div((long)(N + 1) * 4, 256), 256, 0, stream>>>(
        feat, N, 32, st0, st0, g1, b1, FA);
    // 2) conv1 (27, 32->32): FA -> D[:,0:32] (skip);  M_SUB=4 -> 256 rows/block
    conv_mfma_direct<32, 32, 4><<<ceil_div(N, 256), 256, 0, stream>>>(
        FA, nbr_fine, w1t, D, N, 27, N, 64);
    // 3) BN1+ReLU(skip) -> FB [(N+1)x32]
    bn_stats<32><<<256, 256, 0, stream>>>(D, N, 64, st1);
    bn_norm_relu_bf16<32, 32><<<ceil_div((long)(N + 1) * 4, 256), 256, 0, stream>>>(
        D, N, 64, st1, st1, g2, b2, FB);
    // 4) down conv (8, 32->64): FB -> Cf;  M_SUB=2 -> 128 rows/block
    conv_mfma_direct<32, 64, 2><<<ceil_div(M, 128), 256, 0, stream>>>(
        FB, down_idx, wdt, Cf, M, 8, N, 64);
    // 5) BN2+ReLU(Cf) -> FA [(M+1)x64]
    bn_stats<64><<<256, 256, 0, stream>>>(Cf, M, 64, st2);
    bn_norm_relu_bf16<64, 64><<<ceil_div((long)(M + 1) * 8, 256), 256, 0, stream>>>(
        Cf, M, 64, st2, st2, g3, b3, FA);
    // 6) conv2 (27, 64->64): FA -> Cf;  M_SUB=2 -> 128 rows/block
    conv_mfma_direct<64, 64, 2><<<ceil_div(M, 128), 256, 0, stream>>>(
        FA, nbr_coarse, w2t, Cf, M, 27, M, 64);
    // 7) BN3+ReLU(Cf) -> FB [(M+1)x64]
    bn_stats<64><<<256, 256, 0, stream>>>(Cf, M, 64, st3);
    bn_norm_relu_bf16<64, 64><<<ceil_div((long)(M + 1) * 8, 256), 256, 0, stream>>>(
        Cf, M, 64, st3, st3, g4, b4, FB);
    // 8) deconv (64->32): FB -> D[:,32:64]
    deconv_kernel<<<ceil_div((long)N * 8, 256), 256, 0, stream>>>(
        FB, up_cidx, up_k, wup, D, N);
    // 9) BN4+ReLU(D) -> FA [(N+1)x64]; stats: low 32 ch == st1, high 32 from st4
    bn_stats<32><<<256, 256, 0, stream>>>(D + 32, N, 64, st4);
    bn_norm_relu_bf16<64, 32><<<ceil_div((long)(N + 1) * 8, 256), 256, 0, stream>>>(
        D, N, 64, st1, st4, g5, b5, FA);
    // 10) conv3 (27, 64->32): FA -> d_out;  M_SUB=4 -> 256 rows/block
    conv_mfma_direct<64, 32, 4><<<ceil_div(N, 256), 256, 0, stream>>>(
        FA, nbr_fine, w3t, (float*)d_out, N, 27, N, 32);
}